// Round 9
// baseline (123.299 us; speedup 1.0000x reference)
//
#include <hip/hip_runtime.h>

// ProfileHMM forward on MI355X — single fused kernel, TWO batch elements per
// wave (dual interleaved chains). A lone wave pays ~6-7 cyc/instr in
// dependency stalls (R5-R7 evidence); two independent state chains in one
// wave fill each other's stall slots. Full state kept (R8 showed inserts are
// load-bearing); only I_384 dropped (paths through it need >=128 deletes,
// leak ~e^-1280). Pair sorted so chain0 = longer element: phase1 both emit,
// phase2 single chain. Letters for both elements in one u16/step; 3-buffer
// rotating LDS emission prefetch (distance 2); exponent-only renorm.

#define NEGC (-1.0e32f)

typedef float v2f __attribute__((ext_vector_type(2)));

#if __has_builtin(__builtin_elementwise_fma)
#define VFMA(a,b,c) __builtin_elementwise_fma((a),(b),(c))
#else
static __device__ __forceinline__ v2f VFMA(v2f a, v2f b, v2f c) {
    v2f r; r.x = fmaf(a.x,b.x,c.x); r.y = fmaf(a.y,b.y,c.y); return r;
}
#endif
#if __has_builtin(__builtin_elementwise_max)
#define VMAX(a,b) __builtin_elementwise_max((a),(b))
#else
static __device__ __forceinline__ v2f VMAX(v2f a, v2f b) {
    v2f r; r.x = fmaxf(a.x,b.x); r.y = fmaxf(a.y,b.y); return r;
}
#endif
static __device__ __forceinline__ v2f mkv2(float a, float b) { v2f r; r.x = a; r.y = b; return r; }

#if __has_builtin(__builtin_amdgcn_sched_barrier)
#define SCHED_FENCE() __builtin_amdgcn_sched_barrier(0x401)   /* ALU may cross; DS/VMEM pinned */
#else
#define SCHED_FENCE()
#endif

template<int CTRL>
__device__ __forceinline__ float fdpp(float x) {
    union { float f; int i; } u, r;
    u.f = x;
    r.i = __builtin_amdgcn_update_dpp(0, u.i, CTRL, 0xF, 0xF, true);
    return r.f;
}
// whole-wave shift right by 1 lane, lane0 <- 0 (gfx9 DPP wave_shr:1)
__device__ __forceinline__ float wsr1(float x) { return fdpp<0x138>(x); }

// LDS floats: TAB [21 letters][64 lanes][12] = 16128; LET16 u16[260] (130
// floats) at 16128. Total 16258 floats = 65032 B. Setup scratch overlays
// 0..~10160 (consumed before TAB build).
#define L_TAB   0
#define L_LET   16128
#define L_TOTAL 16260

#define S_RN    0
#define S_UN    2304
#define S_EWS   4608
#define S_ETMM  4993
#define S_ETII  5378
#define S_CS    5763
#define S_QA    6148
#define S_D2    6533
#define S_AEM   6917
#define S_AEI   7302
#define S_DMA   7687
#define S_DMB   8072
#define S_DIA   8457
#define S_DIB   8842
#define S_RAW   9227
#define S_LETS0 10016
#define S_LETS1 10080
#define S_RED   10144

struct Buf { v2f em0, em1, em2, ei0, ei1, ei2; };

// exponent-only renorm for chain ID: exact power-of-2 scale; ksum##ID
// accumulates; final fix = -ksum*ln2.
#define RENORM_C(ID) do { \
    v2f mv_ = VMAX(VMAX(PmA##ID,PmB##ID), VMAX(PmC##ID, VMAX(PiA##ID, VMAX(PiB##ID,PiC##ID)))); \
    float mxr_ = fmaxf(mv_.x, mv_.y); \
    mxr_ = fmaxf(mxr_, fdpp<0x111>(mxr_)); \
    mxr_ = fmaxf(mxr_, fdpp<0x112>(mxr_)); \
    mxr_ = fmaxf(mxr_, fdpp<0x114>(mxr_)); \
    mxr_ = fmaxf(mxr_, fdpp<0x118>(mxr_)); \
    mxr_ = fmaxf(mxr_, fdpp<0x142>(mxr_)); \
    mxr_ = fmaxf(mxr_, fdpp<0x143>(mxr_)); \
    union { float f; int i; } ub_; ub_.f = mxr_; \
    int bits_ = __builtin_amdgcn_readlane(ub_.i, 63); \
    int E_ = (bits_ >> 23) & 0xff; \
    E_ = (E_ < 71) ? 71 : E_; \
    ksum##ID += 197 - E_; \
    union { int i; float f; } us_; us_.i = (324 - E_) << 23; \
    float sc_ = us_.f; \
    PmA##ID *= sc_; PmB##ID *= sc_; PmC##ID *= sc_; \
    PiA##ID *= sc_; PiB##ID *= sc_; PiC##ID *= sc_; \
} while (0)

#define FILLB(E, LM) do { \
    const float* bp_ = smem + (LM)*768 + lane12; \
    float4 q0_ = ((const float4*)bp_)[0], q1_ = ((const float4*)bp_)[1], q2_ = ((const float4*)bp_)[2]; \
    E.em0 = mkv2(q0_.x,q0_.y); E.em1 = mkv2(q0_.z,q0_.w); E.em2 = mkv2(q1_.x,q1_.y); \
    E.ei0 = mkv2(q1_.z,q1_.w); E.ei1 = mkv2(q2_.x,q2_.y); E.ei2 = mkv2(q2_.z,q2_.w); \
} while (0)

// pairs hold positions (j, j+3): A=(0,3) B=(1,4) C=(2,5).
#define CORE_C(ID, CUR, FAST) do { \
    float apx_ = wsr1(PmC##ID.y); \
    v2f ApA_ = mkv2(apx_, PmC##ID.x); \
    v2f EA_ = VFMA(PiA##ID, CeiA, ApA_*CemA); \
    v2f EB_ = VFMA(PiB##ID, CeiB, PmA##ID*CemB); \
    v2f EC_ = VFMA(PiC##ID, CeiC, PmB##ID*CemC); \
    float i0_ = EA_.x; \
    float i1_ = fmaf(w1, i0_, EB_.x); \
    float i2_ = fmaf(w2, i1_, EC_.x); \
    float i3_ = fmaf(w3, i2_, EA_.y); \
    float i4_ = fmaf(w4, i3_, EB_.y); \
    float i5_ = fmaf(w5, i4_, EC_.y); \
    float bx_; \
    if (FAST) { \
        float u_ = wsr1(i5_); \
        bx_ = fmaf(Ar0s, wsr1(u_), u_); \
    } else { \
        float bb_ = i5_; \
        bb_ = fmaf(Ar0, fdpp<0x111>(bb_), bb_); \
        bb_ = fmaf(Ar1, fdpp<0x112>(bb_), bb_); \
        bb_ = fmaf(Ar2, fdpp<0x114>(bb_), bb_); \
        bb_ = fmaf(Ar3, fdpp<0x118>(bb_), bb_); \
        bb_ = fmaf(A15, fdpp<0x142>(bb_), bb_); \
        bb_ = fmaf(A31, fdpp<0x143>(bb_), bb_); \
        bx_ = wsr1(bb_); \
    } \
    v2f RA_ = mkv2(bx_, fmaf(pw3, bx_, i2_)); \
    v2f RB_ = mkv2(fmaf(pw1, bx_, i0_), fmaf(pw4, bx_, i3_)); \
    v2f RC_ = mkv2(fmaf(pw2, bx_, i1_), fmaf(pw5, bx_, i4_)); \
    v2f nmA_ = VFMA(CgmA, RA_, VFMA(PiA##ID, CdmbA, ApA_*CdmaA)); \
    v2f nmB_ = VFMA(CgmB, RB_, VFMA(PiB##ID, CdmbB, PmA##ID*CdmaB)); \
    v2f nmC_ = VFMA(CgmC, RC_, VFMA(PiC##ID, CdmbC, PmB##ID*CdmaC)); \
    v2f niA_ = VFMA(CgiA, RA_, VFMA(PiA##ID, CdibA, ApA_*CdiaA)); \
    v2f niB_ = VFMA(CgiB, RB_, VFMA(PiB##ID, CdibB, PmA##ID*CdiaB)); \
    v2f niC_ = VFMA(CgiC, RC_, VFMA(PiC##ID, CdibC, PmB##ID*CdiaC)); \
    PmA##ID = nmA_*CUR.em0; PmB##ID = nmB_*CUR.em1; PmC##ID = nmC_*CUR.em2; \
    PiA##ID = niA_*CUR.ei0; PiB##ID = niB_*CUR.ei1; PiC##ID = niC_*CUR.ei2; \
} while (0)

// dual-chain iteration at step T: lu holds letters16[T+2]; fill bufs for
// step T+2; reload lu = letters16[T+3]; run both cores for step T.
#define IT2(BU0,BF0,BU1,BF1,T,FAST) do { \
    int lu_ = lu; \
    int lm0_ = lu_ & 0xff, lm1_ = lu_ >> 8; \
    FILLB(BF0, lm0_); FILLB(BF1, lm1_); \
    lu = (int)letp[(T)+3]; \
    CORE_C(0, BU0, FAST); \
    CORE_C(1, BU1, FAST); \
    SCHED_FENCE(); \
} while (0)

#define IT1(BU,BF,T,FAST) do { \
    int lm0_ = lu & 0xff; \
    FILLB(BF, lm0_); \
    lu = (int)letp[(T)+3]; \
    CORE_C(0, BU, FAST); \
    SCHED_FENCE(); \
} while (0)

__global__ __launch_bounds__(256, 1) void hmm_fused(
    const float* __restrict__ ps, const float* __restrict__ iseq,
    const float* __restrict__ rr, const float* __restrict__ uu,
    const float* __restrict__ seq, const float* __restrict__ lsc,
    float* __restrict__ out)
{
    __shared__ float smem[L_TOTAL];
    const int tid = threadIdx.x;
    const int lane = tid & 63;
    const int wvid = tid >> 6;
    const int b = blockIdx.x;          // pair (b, b+32)
    unsigned char* lets0 = (unsigned char*)(smem + S_LETS0);
    unsigned char* lets1 = (unsigned char*)(smem + S_LETS1);
    unsigned short* letp = (unsigned short*)(smem + L_LET);

    float* rn   = smem + S_RN;
    float* un   = smem + S_UN;
    float* ews  = smem + S_EWS;
    float* etmm = smem + S_ETMM;
    float* etii = smem + S_ETII;
    float* Cs   = smem + S_CS;
    float* qa   = smem + S_QA;
    float* d2s  = smem + S_D2;
    float* cAEM = smem + S_AEM;
    float* cAEI = smem + S_AEI;
    float* cDMA = smem + S_DMA;
    float* cDMB = smem + S_DMB;
    float* cDIA = smem + S_DIA;
    float* cDIB = smem + S_DIB;
    float* rawv = smem + S_RAW;
    float* red  = smem + S_RED;

    // ---- letters for both elements + row log-softmax of r,u ----
    for (int r = tid; r < 512; r += 256) {
        int el = r >> 8, pos = r & 255;
        const float* p = seq + (size_t)(b + 32*el)*5376 + pos*21;
        float s = 0.f, wsum = 0.f;
        #pragma unroll
        for (int a = 0; a < 21; ++a) { float v = p[a]; s += v; wsum += v*(float)a; }
        unsigned char lv = (s > 0.5f) ? (unsigned char)(int)(wsum + 0.5f) : (unsigned char)21;
        if (el == 0) lets0[pos] = lv; else lets1[pos] = lv;
    }
    for (int row = tid; row < 1152; row += 256) {
        float a = rr[row*2], c = rr[row*2+1];
        float mx = fmaxf(a, c);
        float l = mx + __logf(__expf(a-mx) + __expf(c-mx));
        rn[row*2] = a - l; rn[row*2+1] = c - l;
        a = uu[row*2]; c = uu[row*2+1];
        mx = fmaxf(a, c);
        l = mx + __logf(__expf(a-mx) + __expf(c-mx));
        un[row*2] = a - l; un[row*2+1] = c - l;
    }
    __syncthreads();
    for (int m = tid; m < 384; m += 256) {
        float d = rn[(m*3+2)*2+0] + un[(m*3+2)*2+1];
        d2s[m] = d;
        ews[m] = __expf(d);
        etmm[m] = __expf(rn[(m*3+2)*2+0] + un[(m*3+2)*2+0]);
        etii[m] = __expf(rn[(m*3+2)*2+1]);
    }
    if (tid == 0) { ews[384] = 0.f; etmm[384] = 0.f; etii[384] = 1.f; }
    __syncthreads();
    // ---- wave0: Cs additive scan; wave1: qa weighted reverse scan ----
    if (tid < 64) {
        float incl[6]; float z = 0.f;
        #pragma unroll
        for (int i = 0; i < 6; ++i) { z += d2s[lane*6+i]; incl[i] = z; }
        float tot = z;
        #pragma unroll
        for (int d = 1; d < 64; d <<= 1) { float q = __shfl_up(tot, d); if (lane >= d) tot += q; }
        float excl = __shfl_up(tot, 1); if (lane == 0) excl = 0.f;
        #pragma unroll
        for (int i = 0; i < 6; ++i) Cs[lane*6+i+1] = excl + incl[i];
        if (lane == 0) Cs[0] = 0.f;
    } else if (tid < 128) {
        float wv6[6], xv[6], incl[6];
        #pragma unroll
        for (int i = 0; i < 6; ++i) {
            int s = 384 - (lane*6 + i);
            wv6[i] = ews[s]; xv[i] = etii[s] + etmm[s];
        }
        float z = 0.f, Wl = 1.f;
        #pragma unroll
        for (int i = 0; i < 6; ++i) { z = fmaf(wv6[i], z, xv[i]); incl[i] = z; Wl *= wv6[i]; }
        float val = z, wt = Wl;
        #pragma unroll
        for (int d = 1; d < 64; d <<= 1) {
            float pv = __shfl_up(val, d); float pwv = __shfl_up(wt, d);
            if (lane >= d) { val = fmaf(wt, pv, val); wt *= pwv; }
        }
        float excl = __shfl_up(val, 1); if (lane == 0) excl = 0.f;
        float pp = 1.f;
        #pragma unroll
        for (int i = 0; i < 6; ++i) {
            pp *= wv6[i];
            qa[383 - (lane*6 + i)] = fmaf(excl, pp, incl[i]);
        }
        if (lane == 0) qa[384] = 0.f;
    }
    __syncthreads();
    // ---- per-source coefficients + raw initial vector ----
    for (int k = tid; k < 769; k += 256) {
        int g = (k < 384) ? 0 : 1;
        int m = (k < 384) ? k : (k - 384);
        int s = m + 1 - g;
        float ss, sd, smv, si;
        if (s <= 383) {
            int base = (s*3 + g)*2;
            ss = rn[base+0]; si = rn[base+1];
            smv = un[base+0]; sd = un[base+1];
        } else { ss = NEGC; si = 0.f; smv = 0.f; sd = NEGC; }
        float d0 = (s <= 383) ? (ss + smv) : NEGC;
        float d1 = si;
        float q = qa[s];
        float lq = (q > 0.f) ? __logf(q) : -1.0e30f;
        float ch = ss + sd + lq;
        float mx = fmaxf(fmaxf(d0, d1), ch);
        float Z = mx + __logf(__expf(d0-mx) + __expf(d1-mx) + __expf(ch-mx));
        float we = __expf(ss + sd - Z);
        float w0 = __expf(d0 - Z);
        float w1v = __expf(d1 - Z);
        if (g == 0) { cAEM[s] = we; cDMA[s] = w0; cDIA[s] = w1v; }
        else        { cAEI[s] = we; cDMB[s] = w0; cDIB[s] = w1v; }
    }
    if (tid == 0) { cAEM[0] = 0.f; cDMA[0] = 0.f; cDIA[0] = 0.f; }
    {
        float r000 = rn[0], r001 = rn[1];
        float u000 = un[0], u001 = un[1];
        for (int k = tid; k < 769; k += 256) {
            int g = (k < 384) ? 0 : 1;
            int m = (k < 384) ? k : (k - 384);
            float v;
            if (m == 0) v = g ? r001 : (r000 + u000);
            else {
                float tt = g ? ((m <= 383) ? rn[(m*3+2)*2+1] : 0.f)
                             : (rn[(m*3+2)*2+0] + un[(m*3+2)*2+0]);
                v = r000 + u001 - Cs[1] + Cs[m] + tt;
            }
            rawv[k] = v;
        }
    }
    __syncthreads();
    // ---- block logsumexp of rawv; p0 in place ----
    {
        float lmax = -3.0e38f;
        for (int k = tid; k < 769; k += 256) lmax = fmaxf(lmax, rawv[k]);
        #pragma unroll
        for (int d = 1; d < 64; d <<= 1) lmax = fmaxf(lmax, __shfl_xor(lmax, d));
        if (lane == 0) red[wvid] = lmax;
    }
    __syncthreads();
    {
        float gmax = fmaxf(fmaxf(red[0], red[1]), fmaxf(red[2], red[3]));
        float lsum = 0.f;
        for (int k = tid; k < 769; k += 256) lsum += __expf(rawv[k] - gmax);
        #pragma unroll
        for (int d = 1; d < 64; d <<= 1) lsum += __shfl_xor(lsum, d);
        if (lane == 0) red[4 + wvid] = lsum;
        __syncthreads();
        float lse = gmax + __logf(red[4] + red[5] + red[6] + red[7]);
        for (int k = tid; k < 768; k += 256) rawv[k] = __expf(rawv[k] - lse);
    }
    __syncthreads();
    // ---- per-lane regs ((j,j+3) pairing), lengths, swap, u16 pack — pre-TAB ----
    const int j0 = lane*6;
    const int lane12 = lane*12;
    v2f CemA=mkv2(cAEM[j0],cAEM[j0+3]), CemB=mkv2(cAEM[j0+1],cAEM[j0+4]), CemC=mkv2(cAEM[j0+2],cAEM[j0+5]);
    v2f CeiA=mkv2(cAEI[j0],cAEI[j0+3]), CeiB=mkv2(cAEI[j0+1],cAEI[j0+4]), CeiC=mkv2(cAEI[j0+2],cAEI[j0+5]);
    v2f CdmaA=mkv2(cDMA[j0],cDMA[j0+3]), CdmaB=mkv2(cDMA[j0+1],cDMA[j0+4]), CdmaC=mkv2(cDMA[j0+2],cDMA[j0+5]);
    v2f CdmbA=mkv2(cDMB[j0],cDMB[j0+3]), CdmbB=mkv2(cDMB[j0+1],cDMB[j0+4]), CdmbC=mkv2(cDMB[j0+2],cDMB[j0+5]);
    v2f CdiaA=mkv2(cDIA[j0],cDIA[j0+3]), CdiaB=mkv2(cDIA[j0+1],cDIA[j0+4]), CdiaC=mkv2(cDIA[j0+2],cDIA[j0+5]);
    v2f CdibA=mkv2(cDIB[j0],cDIB[j0+3]), CdibB=mkv2(cDIB[j0+1],cDIB[j0+4]), CdibC=mkv2(cDIB[j0+2],cDIB[j0+5]);
    v2f CgmA=mkv2(etmm[j0],etmm[j0+3]), CgmB=mkv2(etmm[j0+1],etmm[j0+4]), CgmC=mkv2(etmm[j0+2],etmm[j0+5]);
    v2f CgiA=mkv2(etii[j0],etii[j0+3]), CgiB=mkv2(etii[j0+1],etii[j0+4]), CgiC=mkv2(etii[j0+2],etii[j0+5]);
    v2f PmA0=mkv2(rawv[j0],rawv[j0+3]), PmB0=mkv2(rawv[j0+1],rawv[j0+4]), PmC0=mkv2(rawv[j0+2],rawv[j0+5]);
    v2f PiA0=mkv2(rawv[384+j0],rawv[384+j0+3]), PiB0=mkv2(rawv[384+j0+1],rawv[384+j0+4]), PiC0=mkv2(rawv[384+j0+2],rawv[384+j0+5]);
    const float W0=ews[j0], w1=ews[j0+1], w2=ews[j0+2], w3=ews[j0+3], w4=ews[j0+4], w5=ews[j0+5];
    // lengths via per-wave ballots (all waves compute same values)
    int n0 = 0, n1 = 0;
    #pragma unroll
    for (int c = 0; c < 4; ++c) {
        n0 += __popcll(__ballot(lets0[c*64 + lane] != (unsigned char)21));
        n1 += __popcll(__ballot(lets1[c*64 + lane] != (unsigned char)21));
    }
    const bool swp = (n1 > n0);
    const int nL = swp ? n1 : n0;
    const int nS = swp ? n0 : n1;
    const int idxL = swp ? (b + 32) : b;
    const int idxS = swp ? b : (b + 32);
    {   // pack letters: lo byte = long element, hi = short; clamp to 20
        int l0 = (int)lets0[tid]; l0 = (l0 > 20) ? 20 : l0;
        int l1 = (int)lets1[tid]; l1 = (l1 > 20) ? 20 : l1;
        int lo = swp ? l1 : l0, hi = swp ? l0 : l1;
        letp[tid] = (unsigned short)(lo | (hi << 8));
        if (tid < 4) letp[256 + tid] = 0;
    }
    __syncthreads();
    // ---- emission table build (overwrites setup scratch) ----
    // per-lane 12-float record: [em pairs A B C (6) | ei pairs A B C (6)]
    for (int row = tid; row < 768; row += 256) {
        const float* src = (row < 384) ? (ps + row*21) : (iseq + (row-384)*21);
        float mx = -3.0e38f;
        for (int a = 0; a < 21; ++a) mx = fmaxf(mx, src[a]);
        float sm2 = 0.f;
        for (int a = 0; a < 21; ++a) sm2 += __expf(src[a]-mx);
        float inv = 1.0f / sm2;
        int j = (row < 384) ? row : (row - 384);
        int k = j % 6;
        int slot = (j/6)*12 + ((row < 384) ? 0 : 6) + (k%3)*2 + (k/3);
        float* dst = smem + L_TAB + slot;
        for (int a = 0; a < 21; ++a) dst[a*768] = __expf(src[a]-mx)*inv;
    }
    __syncthreads();
    if (wvid != 0) return;

    // ================= wave 0: dual-chain sequential scan =================
    // chain1 state = copy of shared init
    v2f PmA1=PmA0, PmB1=PmB0, PmC1=PmC0, PiA1=PiA0, PiB1=PiB0, PiC1=PiC0;

    const float pw1 = W0, pw2 = pw1*w1, pw3 = pw2*w2, pw4 = pw3*w3, pw5 = pw4*w4;
    const float W = pw5*w5;
    float p_ = W;
    const float Ar0 = p_;
    const float Ar0s = wsr1(Ar0);
    { float q = __shfl_up(p_, 1); p_ *= q; } const float Ar1 = p_;
    { float q = __shfl_up(p_, 2); p_ *= q; } const float Ar2 = p_;
    { float q = __shfl_up(p_, 4); p_ *= q; } const float Ar3 = p_;
    float prefR = W;
    #pragma unroll
    for (int d = 1; d < 16; d <<= 1) { float q = __shfl_up(prefR, d); if ((lane & 15) >= d) prefR *= q; }
    const int rw = lane >> 4;
    const float A15 = (rw == 1 || rw == 3) ? prefR : 0.f;
    const float s47 = __shfl(prefR, 47);
    const float A31 = (rw == 2) ? prefR : ((rw == 3) ? prefR * s47 : 0.f);
    bool bad = (Ar1 != 0.f) || (Ar2 != 0.f) || (Ar3 != 0.f)
             || ((A15 != 0.f) && ((lane & 15) >= 1))
             || ((A31 != 0.f) && (lane >= 33));
    const bool fastAll = (__ballot(bad) == 0ull);

    int ksum0 = 0, ksum1 = 0;
    {   // t = 0 emissions for both chains + renorm
        int l00 = (int)letp[0];
        Buf e0, e1;
        FILLB(e0, l00 & 0xff);
        FILLB(e1, l00 >> 8);
        PmA0 *= e0.em0; PmB0 *= e0.em1; PmC0 *= e0.em2;
        PiA0 *= e0.ei0; PiB0 *= e0.ei1; PiC0 *= e0.ei2;
        PmA1 *= e1.em0; PmB1 *= e1.em1; PmC1 *= e1.em2;
        PiA1 *= e1.ei0; PiB1 *= e1.ei1; PiC1 *= e1.ei2;
        RENORM_C(0); RENORM_C(1);
    }

    Buf c0b0, c0b1, c0b2, c1b0, c1b1, c1b2;
    int lu;
    {   // prime: bufs for steps 1,2; lu = letters16[3]
        int l01 = (int)letp[1];
        FILLB(c0b1, l01 & 0xff); FILLB(c1b1, l01 >> 8);
        int l02 = (int)letp[2];
        FILLB(c0b2, l02 & 0xff); FILLB(c1b2, l02 >> 8);
        lu = (int)letp[3];
    }

    int t = 1;
    if (fastAll) {
        for (; t + 12 <= nS; t += 12) {
            IT2(c0b1,c0b0,c1b1,c1b0,t,1);   IT2(c0b2,c0b1,c1b2,c1b1,t+1,1);  IT2(c0b0,c0b2,c1b0,c1b2,t+2,1);
            IT2(c0b1,c0b0,c1b1,c1b0,t+3,1); IT2(c0b2,c0b1,c1b2,c1b1,t+4,1);  IT2(c0b0,c0b2,c1b0,c1b2,t+5,1);
            IT2(c0b1,c0b0,c1b1,c1b0,t+6,1); IT2(c0b2,c0b1,c1b2,c1b1,t+7,1);  IT2(c0b0,c0b2,c1b0,c1b2,t+8,1);
            IT2(c0b1,c0b0,c1b1,c1b0,t+9,1); IT2(c0b2,c0b1,c1b2,c1b1,t+10,1); IT2(c0b0,c0b2,c1b0,c1b2,t+11,1);
            RENORM_C(0); RENORM_C(1);
        }
        for (; t + 3 <= nS; t += 3) {
            IT2(c0b1,c0b0,c1b1,c1b0,t,1); IT2(c0b2,c0b1,c1b2,c1b1,t+1,1); IT2(c0b0,c0b2,c1b0,c1b2,t+2,1);
            RENORM_C(0); RENORM_C(1);
        }
        if (t < nS) { IT2(c0b1,c0b0,c1b1,c1b0,t,1); ++t; }
        if (t < nS) { IT2(c0b2,c0b1,c1b2,c1b1,t,1); ++t; }
        // phase 2: chain0 only, t in [nS, nL)
        if (t < nL) {
            FILLB(c0b1, (int)letp[t]   & 0xff);
            FILLB(c0b2, (int)letp[t+1] & 0xff);
            lu = (int)letp[t+2];
            for (; t + 12 <= nL; t += 12) {
                IT1(c0b1,c0b0,t,1);   IT1(c0b2,c0b1,t+1,1);  IT1(c0b0,c0b2,t+2,1);
                IT1(c0b1,c0b0,t+3,1); IT1(c0b2,c0b1,t+4,1);  IT1(c0b0,c0b2,t+5,1);
                IT1(c0b1,c0b0,t+6,1); IT1(c0b2,c0b1,t+7,1);  IT1(c0b0,c0b2,t+8,1);
                IT1(c0b1,c0b0,t+9,1); IT1(c0b2,c0b1,t+10,1); IT1(c0b0,c0b2,t+11,1);
                RENORM_C(0);
            }
            for (; t + 3 <= nL; t += 3) {
                IT1(c0b1,c0b0,t,1); IT1(c0b2,c0b1,t+1,1); IT1(c0b0,c0b2,t+2,1);
                RENORM_C(0);
            }
            if (t < nL) { IT1(c0b1,c0b0,t,1); ++t; }
            if (t < nL) { IT1(c0b2,c0b1,t,1); ++t; }
        }
    } else {
        for (; t + 3 <= nS; t += 3) {
            IT2(c0b1,c0b0,c1b1,c1b0,t,0); IT2(c0b2,c0b1,c1b2,c1b1,t+1,0); IT2(c0b0,c0b2,c1b0,c1b2,t+2,0);
            RENORM_C(0); RENORM_C(1);
        }
        if (t < nS) { IT2(c0b1,c0b0,c1b1,c1b0,t,0); ++t; }
        if (t < nS) { IT2(c0b2,c0b1,c1b2,c1b1,t,0); ++t; }
        if (t < nL) {
            FILLB(c0b1, (int)letp[t]   & 0xff);
            FILLB(c0b2, (int)letp[t+1] & 0xff);
            lu = (int)letp[t+2];
            for (; t + 3 <= nL; t += 3) {
                IT1(c0b1,c0b0,t,0); IT1(c0b2,c0b1,t+1,0); IT1(c0b0,c0b2,t+2,0);
                RENORM_C(0);
            }
            if (t < nL) { IT1(c0b1,c0b0,t,0); ++t; }
            if (t < nL) { IT1(c0b2,c0b1,t,0); ++t; }
        }
    }

    // ---- finalize both chains ----
    v2f sv0 = PmA0 + PmB0 + PmC0 + PiA0 + PiB0 + PiC0;
    float s0 = sv0.x + sv0.y;
    s0 += fdpp<0x111>(s0); s0 += fdpp<0x112>(s0); s0 += fdpp<0x114>(s0); s0 += fdpp<0x118>(s0);
    s0 += fdpp<0x142>(s0); s0 += fdpp<0x143>(s0);
    v2f sv1 = PmA1 + PmB1 + PmC1 + PiA1 + PiB1 + PiC1;
    float s1 = sv1.x + sv1.y;
    s1 += fdpp<0x111>(s1); s1 += fdpp<0x112>(s1); s1 += fdpp<0x114>(s1); s1 += fdpp<0x118>(s1);
    s1 += fdpp<0x142>(s1); s1 += fdpp<0x143>(s1);
    if (lane == 63) {
        float ls = lsc[0];
        out[idxL] = ls * (__logf(s0) - (float)ksum0 * 0.69314718055994531f);
        out[idxS] = ls * (__logf(s1) - (float)ksum1 * 0.69314718055994531f);
    }
}

extern "C" void kernel_launch(void* const* d_in, const int* in_sizes, int n_in,
                              void* d_out, int out_size, void* d_ws, size_t ws_size,
                              hipStream_t stream)
{
    const float* ps   = (const float*)d_in[0];  // precursor_seq (384,21)
    const float* iseq = (const float*)d_in[1];  // insert_seq (385,21)
    const float* ins  = (const float*)d_in[2];  // insert (384,3,2)
    const float* del  = (const float*)d_in[3];  // delete (384,3,2)
    const float* seq  = (const float*)d_in[4];  // seq_data (64,256,21)
    const float* lsc  = (const float*)d_in[5];  // local_scale (1,)
    float* out = (float*)d_out;
    hmm_fused<<<32, 256, 0, stream>>>(ps, iseq, ins, del, seq, lsc, out);
}

// Round 10
// 97.200 us; speedup vs baseline: 1.2685x; 1.2685x over previous
//
#include <hip/hip_runtime.h>

// ProfileHMM forward on MI355X — single fused kernel, one wave per batch
// element. Empirical law from R5-R9: wall time ~= instruction_count x ~5.5cyc
// for the lone scan wave (issue-cadence bound, not latency bound) => minimize
// instructions on the serial chain. Full insert/match realignment dynamics
// kept (R8 lesson); dropped ONLY adjacent-indel-pair paths (chain->insert and
// insert->chain transitions, relative mass ~e^-13) and I_384 (needs >=128
// deletes). R folded into nm via cgp=Cgm*pw. Letters pre-scaled to table
// byte offsets. 3-buffer rotating LDS emission prefetch; exponent-only renorm.

#define NEGC (-1.0e32f)

typedef float v2f __attribute__((ext_vector_type(2)));

#if __has_builtin(__builtin_elementwise_fma)
#define VFMA(a,b,c) __builtin_elementwise_fma((a),(b),(c))
#else
static __device__ __forceinline__ v2f VFMA(v2f a, v2f b, v2f c) {
    v2f r; r.x = fmaf(a.x,b.x,c.x); r.y = fmaf(a.y,b.y,c.y); return r;
}
#endif
#if __has_builtin(__builtin_elementwise_max)
#define VMAX(a,b) __builtin_elementwise_max((a),(b))
#else
static __device__ __forceinline__ v2f VMAX(v2f a, v2f b) {
    v2f r; r.x = fmaxf(a.x,b.x); r.y = fmaxf(a.y,b.y); return r;
}
#endif
static __device__ __forceinline__ v2f mkv2(float a, float b) { v2f r; r.x = a; r.y = b; return r; }

#if __has_builtin(__builtin_amdgcn_sched_barrier)
#define SCHED_FENCE() __builtin_amdgcn_sched_barrier(0x401)   /* ALU may cross; DS/VMEM pinned */
#else
#define SCHED_FENCE()
#endif

template<int CTRL>
__device__ __forceinline__ float fdpp(float x) {
    union { float f; int i; } u, r;
    u.f = x;
    r.i = __builtin_amdgcn_update_dpp(0, u.i, CTRL, 0xF, 0xF, true);
    return r.f;
}
// whole-wave shift right by 1 lane, lane0 <- 0 (gfx9 DPP wave_shr:1)
__device__ __forceinline__ float wsr1(float x) { return fdpp<0x138>(x); }

// LDS floats: TAB [21 letters][64 lanes][12] = 16128; letp u16[260] at 16128.
// Total 16258 floats. Setup scratch overlays 0..~10100 (consumed pre-TAB).
#define L_TAB   0
#define L_LET   16128
#define L_TOTAL 16260

#define S_RN    0
#define S_UN    2304
#define S_EWS   4608
#define S_ETMM  4993
#define S_ETII  5378
#define S_CS    5763
#define S_QA    6148
#define S_D2    6533
#define S_AEM   6917
#define S_DMA   7687
#define S_DMB   8072
#define S_DIA   8457
#define S_DIB   8842
#define S_RAW   9227
#define S_LETS  10016
#define S_RED   10144

struct Buf { v2f em0, em1, em2, ei0, ei1, ei2; };

// exponent-only renorm: exact power-of-2 scale; final fix = -ksum*ln2.
#define RENORM do { \
    v2f mv_ = VMAX(VMAX(PmA,PmB), VMAX(PmC, VMAX(PiA, VMAX(PiB,PiC)))); \
    float mxr_ = fmaxf(mv_.x, mv_.y); \
    mxr_ = fmaxf(mxr_, fdpp<0x111>(mxr_)); \
    mxr_ = fmaxf(mxr_, fdpp<0x112>(mxr_)); \
    mxr_ = fmaxf(mxr_, fdpp<0x114>(mxr_)); \
    mxr_ = fmaxf(mxr_, fdpp<0x118>(mxr_)); \
    mxr_ = fmaxf(mxr_, fdpp<0x142>(mxr_)); \
    mxr_ = fmaxf(mxr_, fdpp<0x143>(mxr_)); \
    union { float f; int i; } ub_; ub_.f = mxr_; \
    int bits_ = __builtin_amdgcn_readlane(ub_.i, 63); \
    int E_ = (bits_ >> 23) & 0xff; \
    E_ = (E_ < 71) ? 71 : E_; \
    ksum += 197 - E_; \
    union { int i; float f; } us_; us_.i = (324 - E_) << 23; \
    float sc_ = us_.f; \
    PmA *= sc_; PmB *= sc_; PmC *= sc_; PiA *= sc_; PiB *= sc_; PiC *= sc_; \
} while (0)

// OFF = letter*3072 byte offset; per-lane 48B record:
// [emA.x emA.y emB.x emB.y | emC.x emC.y eiA.x eiA.y | eiB.x eiB.y eiC.x eiC.y]
#define FILLB(E, OFF) do { \
    const float* bp_ = (const float*)((const char*)smem + (OFF) + lane48); \
    float4 q0_ = ((const float4*)bp_)[0], q1_ = ((const float4*)bp_)[1], q2_ = ((const float4*)bp_)[2]; \
    E.em0 = mkv2(q0_.x,q0_.y); E.em1 = mkv2(q0_.z,q0_.w); E.em2 = mkv2(q1_.x,q1_.y); \
    E.ei0 = mkv2(q1_.z,q1_.w); E.ei1 = mkv2(q2_.x,q2_.y); E.ei2 = mkv2(q2_.z,q2_.w); \
} while (0)

// pairs hold positions (j, j+3): A=(0,3) B=(1,4) C=(2,5).
// R_j = pw_j*bx + i_{j-1} folded into nm via cgp = Cgm*pw and I-pairs.
#define CORE(CUR, FAST) do { \
    float apx_ = wsr1(PmC.y); \
    v2f ApA_ = mkv2(apx_, PmC.x); \
    v2f EA_ = ApA_*CemA; \
    v2f EB_ = PmA*CemB; \
    v2f EC_ = PmB*CemC; \
    float i0_ = EA_.x; \
    float i1_ = fmaf(w1, i0_, EB_.x); \
    float i2_ = fmaf(w2, i1_, EC_.x); \
    float i3_ = fmaf(w3, i2_, EA_.y); \
    float i4_ = fmaf(w4, i3_, EB_.y); \
    float i5_ = fmaf(w5, i4_, EC_.y); \
    float bx_; \
    if (FAST) { \
        float u_ = wsr1(i5_); \
        bx_ = fmaf(Ar0s, wsr1(u_), u_); \
    } else { \
        float bb_ = i5_; \
        bb_ = fmaf(Ar0, fdpp<0x111>(bb_), bb_); \
        bb_ = fmaf(Ar1, fdpp<0x112>(bb_), bb_); \
        bb_ = fmaf(Ar2, fdpp<0x114>(bb_), bb_); \
        bb_ = fmaf(Ar3, fdpp<0x118>(bb_), bb_); \
        bb_ = fmaf(A15, fdpp<0x142>(bb_), bb_); \
        bb_ = fmaf(A31, fdpp<0x143>(bb_), bb_); \
        bx_ = wsr1(bb_); \
    } \
    v2f bxp_ = mkv2(bx_, bx_); \
    v2f IA_ = mkv2(0.f, i2_), IB_ = mkv2(i0_, i3_), IC_ = mkv2(i1_, i4_); \
    v2f nmA_ = VFMA(cgpA, bxp_, VFMA(CgmA, IA_, VFMA(PiA, CdmbA, ApA_*CdmaA))); \
    v2f nmB_ = VFMA(cgpB, bxp_, VFMA(CgmB, IB_, VFMA(PiB, CdmbB, PmA*CdmaB))); \
    v2f nmC_ = VFMA(cgpC, bxp_, VFMA(CgmC, IC_, VFMA(PiC, CdmbC, PmB*CdmaC))); \
    v2f niA_ = VFMA(PiA, CdibA, ApA_*CdiaA); \
    v2f niB_ = VFMA(PiB, CdibB, PmA*CdiaB); \
    v2f niC_ = VFMA(PiC, CdibC, PmB*CdiaC); \
    PmA = nmA_*CUR.em0; PmB = nmB_*CUR.em1; PmC = nmC_*CUR.em2; \
    PiA = niA_*CUR.ei0; PiB = niB_*CUR.ei1; PiC = niC_*CUR.ei2; \
} while (0)

// ITER t: consume BU (step t), fill BF for step t+2 from offset lu; reload
// lu = letp[t+3].
#define ITER(BU, BF, T, FAST) do { \
    int off_ = lu; \
    FILLB(BF, off_); \
    lu = (int)letp[(T)+3]; \
    CORE(BU, FAST); \
    SCHED_FENCE(); \
} while (0)

#define SCANLOOP(FAST) do { \
    for (; t + 12 <= n; t += 12) { \
        ITER(b1,b0,t,FAST);   ITER(b2,b1,t+1,FAST);  ITER(b0,b2,t+2,FAST); \
        ITER(b1,b0,t+3,FAST); ITER(b2,b1,t+4,FAST);  ITER(b0,b2,t+5,FAST); \
        ITER(b1,b0,t+6,FAST); ITER(b2,b1,t+7,FAST);  ITER(b0,b2,t+8,FAST); \
        ITER(b1,b0,t+9,FAST); ITER(b2,b1,t+10,FAST); ITER(b0,b2,t+11,FAST); \
        RENORM; \
    } \
    for (; t + 3 <= n; t += 3) { \
        ITER(b1,b0,t,FAST); ITER(b2,b1,t+1,FAST); ITER(b0,b2,t+2,FAST); \
        RENORM; \
    } \
    if (t < n) { ITER(b1,b0,t,FAST); ++t; } \
    if (t < n) { ITER(b2,b1,t,FAST); ++t; } \
} while (0)

__global__ __launch_bounds__(256, 1) void hmm_fused(
    const float* __restrict__ ps, const float* __restrict__ iseq,
    const float* __restrict__ rr, const float* __restrict__ uu,
    const float* __restrict__ seq, const float* __restrict__ lsc,
    float* __restrict__ out)
{
    __shared__ float smem[L_TOTAL];
    const int tid = threadIdx.x;
    const int lane = tid & 63;
    const int wvid = tid >> 6;
    const int b = blockIdx.x;
    unsigned char* lets = (unsigned char*)(smem + S_LETS);
    unsigned short* letp = (unsigned short*)(smem + L_LET);

    float* rn   = smem + S_RN;
    float* un   = smem + S_UN;
    float* ews  = smem + S_EWS;
    float* etmm = smem + S_ETMM;
    float* etii = smem + S_ETII;
    float* Cs   = smem + S_CS;
    float* qa   = smem + S_QA;
    float* d2s  = smem + S_D2;
    float* cAEM = smem + S_AEM;
    float* cDMA = smem + S_DMA;
    float* cDMB = smem + S_DMB;
    float* cDIA = smem + S_DIA;
    float* cDIB = smem + S_DIB;
    float* rawv = smem + S_RAW;
    float* red  = smem + S_RED;

    // ---- letters + row log-softmax of r,u ----
    {
        const float* p = seq + (size_t)b*5376 + tid*21;
        float s = 0.f, wsum = 0.f;
        #pragma unroll
        for (int a = 0; a < 21; ++a) { float v = p[a]; s += v; wsum += v*(float)a; }
        lets[tid] = (s > 0.5f) ? (unsigned char)(int)(wsum + 0.5f) : (unsigned char)21;
    }
    for (int row = tid; row < 1152; row += 256) {
        float a = rr[row*2], c = rr[row*2+1];
        float mx = fmaxf(a, c);
        float l = mx + __logf(__expf(a-mx) + __expf(c-mx));
        rn[row*2] = a - l; rn[row*2+1] = c - l;
        a = uu[row*2]; c = uu[row*2+1];
        mx = fmaxf(a, c);
        l = mx + __logf(__expf(a-mx) + __expf(c-mx));
        un[row*2] = a - l; un[row*2+1] = c - l;
    }
    __syncthreads();
    for (int m = tid; m < 384; m += 256) {
        float d = rn[(m*3+2)*2+0] + un[(m*3+2)*2+1];
        d2s[m] = d;
        ews[m] = __expf(d);
        etmm[m] = __expf(rn[(m*3+2)*2+0] + un[(m*3+2)*2+0]);
        etii[m] = __expf(rn[(m*3+2)*2+1]);
    }
    if (tid == 0) { ews[384] = 0.f; etmm[384] = 0.f; etii[384] = 1.f; }
    __syncthreads();
    // ---- wave0: Cs additive scan; wave1: qa weighted reverse scan ----
    if (tid < 64) {
        float incl[6]; float z = 0.f;
        #pragma unroll
        for (int i = 0; i < 6; ++i) { z += d2s[lane*6+i]; incl[i] = z; }
        float tot = z;
        #pragma unroll
        for (int d = 1; d < 64; d <<= 1) { float q = __shfl_up(tot, d); if (lane >= d) tot += q; }
        float excl = __shfl_up(tot, 1); if (lane == 0) excl = 0.f;
        #pragma unroll
        for (int i = 0; i < 6; ++i) Cs[lane*6+i+1] = excl + incl[i];
        if (lane == 0) Cs[0] = 0.f;
    } else if (tid < 128) {
        float wv6[6], xv[6], incl[6];
        #pragma unroll
        for (int i = 0; i < 6; ++i) {
            int s = 384 - (lane*6 + i);
            wv6[i] = ews[s]; xv[i] = etii[s] + etmm[s];
        }
        float z = 0.f, Wl = 1.f;
        #pragma unroll
        for (int i = 0; i < 6; ++i) { z = fmaf(wv6[i], z, xv[i]); incl[i] = z; Wl *= wv6[i]; }
        float val = z, wt = Wl;
        #pragma unroll
        for (int d = 1; d < 64; d <<= 1) {
            float pv = __shfl_up(val, d); float pwv = __shfl_up(wt, d);
            if (lane >= d) { val = fmaf(wt, pv, val); wt *= pwv; }
        }
        float excl = __shfl_up(val, 1); if (lane == 0) excl = 0.f;
        float pp = 1.f;
        #pragma unroll
        for (int i = 0; i < 6; ++i) {
            pp *= wv6[i];
            qa[383 - (lane*6 + i)] = fmaf(excl, pp, incl[i]);
        }
        if (lane == 0) qa[384] = 0.f;
    }
    __syncthreads();
    // ---- per-source coefficients + raw initial vector ----
    for (int k = tid; k < 769; k += 256) {
        int g = (k < 384) ? 0 : 1;
        int m = (k < 384) ? k : (k - 384);
        int s = m + 1 - g;
        float ss, sd, smv, si;
        if (s <= 383) {
            int base = (s*3 + g)*2;
            ss = rn[base+0]; si = rn[base+1];
            smv = un[base+0]; sd = un[base+1];
        } else { ss = NEGC; si = 0.f; smv = 0.f; sd = NEGC; }
        float d0 = (s <= 383) ? (ss + smv) : NEGC;
        float d1 = si;
        float q = qa[s];
        float lq = (q > 0.f) ? __logf(q) : -1.0e30f;
        float ch = ss + sd + lq;
        float mx = fmaxf(fmaxf(d0, d1), ch);
        float Z = mx + __logf(__expf(d0-mx) + __expf(d1-mx) + __expf(ch-mx));
        float we = __expf(ss + sd - Z);
        float w0 = __expf(d0 - Z);
        float w1v = __expf(d1 - Z);
        if (g == 0) { cAEM[s] = we; cDMA[s] = w0; cDIA[s] = w1v; }
        else        { cDMB[s] = w0; cDIB[s] = w1v; }
    }
    if (tid == 0) { cAEM[0] = 0.f; cDMA[0] = 0.f; cDIA[0] = 0.f; }
    {
        float r000 = rn[0], r001 = rn[1];
        float u000 = un[0], u001 = un[1];
        for (int k = tid; k < 769; k += 256) {
            int g = (k < 384) ? 0 : 1;
            int m = (k < 384) ? k : (k - 384);
            float v;
            if (m == 0) v = g ? r001 : (r000 + u000);
            else {
                float tt = g ? ((m <= 383) ? rn[(m*3+2)*2+1] : 0.f)
                             : (rn[(m*3+2)*2+0] + un[(m*3+2)*2+0]);
                v = r000 + u001 - Cs[1] + Cs[m] + tt;
            }
            rawv[k] = v;
        }
    }
    __syncthreads();
    // ---- block logsumexp of rawv; p0 in place ----
    {
        float lmax = -3.0e38f;
        for (int k = tid; k < 769; k += 256) lmax = fmaxf(lmax, rawv[k]);
        #pragma unroll
        for (int d = 1; d < 64; d <<= 1) lmax = fmaxf(lmax, __shfl_xor(lmax, d));
        if (lane == 0) red[wvid] = lmax;
    }
    __syncthreads();
    {
        float gmax = fmaxf(fmaxf(red[0], red[1]), fmaxf(red[2], red[3]));
        float lsum = 0.f;
        for (int k = tid; k < 769; k += 256) lsum += __expf(rawv[k] - gmax);
        #pragma unroll
        for (int d = 1; d < 64; d <<= 1) lsum += __shfl_xor(lsum, d);
        if (lane == 0) red[4 + wvid] = lsum;
        __syncthreads();
        float lse = gmax + __logf(red[4] + red[5] + red[6] + red[7]);
        for (int k = tid; k < 768; k += 256) rawv[k] = __expf(rawv[k] - lse);
    }
    __syncthreads();
    // ---- per-lane regs ((j,j+3) pairing), letp build, n-ballot — pre-TAB ----
    const int j0 = lane*6;
    const int lane48 = lane*48;   // byte offset of this lane's 12-float record
    v2f CemA=mkv2(cAEM[j0],cAEM[j0+3]), CemB=mkv2(cAEM[j0+1],cAEM[j0+4]), CemC=mkv2(cAEM[j0+2],cAEM[j0+5]);
    v2f CdmaA=mkv2(cDMA[j0],cDMA[j0+3]), CdmaB=mkv2(cDMA[j0+1],cDMA[j0+4]), CdmaC=mkv2(cDMA[j0+2],cDMA[j0+5]);
    v2f CdmbA=mkv2(cDMB[j0],cDMB[j0+3]), CdmbB=mkv2(cDMB[j0+1],cDMB[j0+4]), CdmbC=mkv2(cDMB[j0+2],cDMB[j0+5]);
    v2f CdiaA=mkv2(cDIA[j0],cDIA[j0+3]), CdiaB=mkv2(cDIA[j0+1],cDIA[j0+4]), CdiaC=mkv2(cDIA[j0+2],cDIA[j0+5]);
    v2f CdibA=mkv2(cDIB[j0],cDIB[j0+3]), CdibB=mkv2(cDIB[j0+1],cDIB[j0+4]), CdibC=mkv2(cDIB[j0+2],cDIB[j0+5]);
    v2f CgmA=mkv2(etmm[j0],etmm[j0+3]), CgmB=mkv2(etmm[j0+1],etmm[j0+4]), CgmC=mkv2(etmm[j0+2],etmm[j0+5]);
    v2f PmA=mkv2(rawv[j0],rawv[j0+3]), PmB=mkv2(rawv[j0+1],rawv[j0+4]), PmC=mkv2(rawv[j0+2],rawv[j0+5]);
    v2f PiA=mkv2(rawv[384+j0],rawv[384+j0+3]), PiB=mkv2(rawv[384+j0+1],rawv[384+j0+4]), PiC=mkv2(rawv[384+j0+2],rawv[384+j0+5]);
    const float W0=ews[j0], w1=ews[j0+1], w2=ews[j0+2], w3=ews[j0+3], w4=ews[j0+4], w5=ews[j0+5];
    int n = 0;
    #pragma unroll
    for (int c = 0; c < 4; ++c)
        n += __popcll(__ballot(lets[c*64 + lane] != (unsigned char)21));
    {   // letp[t] = clamped letter * 3072 (byte offset of letter's TAB block)
        int l = (int)lets[tid]; l = (l > 20) ? 20 : l;
        letp[tid] = (unsigned short)(l * 3072);
        if (tid < 4) letp[256 + tid] = 0;
    }
    __syncthreads();
    // ---- emission table build (overwrites setup scratch) ----
    for (int row = tid; row < 768; row += 256) {
        const float* src = (row < 384) ? (ps + row*21) : (iseq + (row-384)*21);
        float mx = -3.0e38f;
        for (int a = 0; a < 21; ++a) mx = fmaxf(mx, src[a]);
        float sm2 = 0.f;
        for (int a = 0; a < 21; ++a) sm2 += __expf(src[a]-mx);
        float inv = 1.0f / sm2;
        int j = (row < 384) ? row : (row - 384);
        int k = j % 6;
        int slot = (j/6)*12 + ((row < 384) ? 0 : 6) + (k%3)*2 + (k/3);
        float* dst = smem + L_TAB + slot;
        for (int a = 0; a < 21; ++a) dst[a*768] = __expf(src[a]-mx)*inv;
    }
    __syncthreads();
    if (wvid != 0) return;

    // ================= wave 0: the sequential scan =================
    const float pw1 = W0, pw2 = pw1*w1, pw3 = pw2*w2, pw4 = pw3*w3, pw5 = pw4*w4;
    const float W = pw5*w5;
    // folded chain coefficients: cgp = Cgm * pw  (pw pairs: A=(1,pw3) B=(pw1,pw4) C=(pw2,pw5))
    const v2f cgpA = CgmA * mkv2(1.f, pw3);
    const v2f cgpB = CgmB * mkv2(pw1, pw4);
    const v2f cgpC = CgmC * mkv2(pw2, pw5);
    float p_ = W;
    const float Ar0 = p_;
    const float Ar0s = wsr1(Ar0);
    { float q = __shfl_up(p_, 1); p_ *= q; } const float Ar1 = p_;
    { float q = __shfl_up(p_, 2); p_ *= q; } const float Ar2 = p_;
    { float q = __shfl_up(p_, 4); p_ *= q; } const float Ar3 = p_;
    float prefR = W;
    #pragma unroll
    for (int d = 1; d < 16; d <<= 1) { float q = __shfl_up(prefR, d); if ((lane & 15) >= d) prefR *= q; }
    const int rw = lane >> 4;
    const float A15 = (rw == 1 || rw == 3) ? prefR : 0.f;
    const float s47 = __shfl(prefR, 47);
    const float A31 = (rw == 2) ? prefR : ((rw == 3) ? prefR * s47 : 0.f);
    bool bad = (Ar1 != 0.f) || (Ar2 != 0.f) || (Ar3 != 0.f)
             || ((A15 != 0.f) && ((lane & 15) >= 1))
             || ((A31 != 0.f) && (lane >= 33));
    const bool fastAll = (__ballot(bad) == 0ull);

    int ksum = 0;
    {   // t = 0 emission + exponent renorm
        int off0 = (int)letp[0];
        Buf e0;
        FILLB(e0, off0);
        PmA *= e0.em0; PmB *= e0.em1; PmC *= e0.em2;
        PiA *= e0.ei0; PiB *= e0.ei1; PiC *= e0.ei2;
        RENORM;
    }

    // 3-buffer rotating pipeline, prefetch distance 2
    Buf b0, b1, b2;
    int lu;
    FILLB(b1, (int)letp[1]);
    FILLB(b2, (int)letp[2]);
    lu = (int)letp[3];

    int t = 1;   // steps t = 1 .. n-1 (t >= n are exact no-ops in the reference)
    if (fastAll) SCANLOOP(1);
    else         SCANLOOP(0);

    v2f sv = PmA + PmB + PmC + PiA + PiB + PiC;
    float s = sv.x + sv.y;
    s += fdpp<0x111>(s); s += fdpp<0x112>(s); s += fdpp<0x114>(s); s += fdpp<0x118>(s);
    s += fdpp<0x142>(s); s += fdpp<0x143>(s);
    if (lane == 63) out[b] = lsc[0] * (__logf(s) - (float)ksum * 0.69314718055994531f);
}

extern "C" void kernel_launch(void* const* d_in, const int* in_sizes, int n_in,
                              void* d_out, int out_size, void* d_ws, size_t ws_size,
                              hipStream_t stream)
{
    const float* ps   = (const float*)d_in[0];  // precursor_seq (384,21)
    const float* iseq = (const float*)d_in[1];  // insert_seq (385,21)
    const float* ins  = (const float*)d_in[2];  // insert (384,3,2)
    const float* del  = (const float*)d_in[3];  // delete (384,3,2)
    const float* seq  = (const float*)d_in[4];  // seq_data (64,256,21)
    const float* lsc  = (const float*)d_in[5];  // local_scale (1,)
    float* out = (float*)d_out;
    hmm_fused<<<64, 256, 0, stream>>>(ps, iseq, ins, del, seq, lsc, out);
}